// Round 16
// baseline (178.540 us; speedup 1.0000x reference)
//
#include <hip/hip_runtime.h>
#include <hip/hip_bf16.h>

#define IN_F 108   // concat(x[107], votes[1])
#define XD   107
#define HID  128
#define OUTD 64
#define BSH 6              // bucket = dst >> 6 (64 nodes per bucket)
#define BNODES 64
#define MAXBK 1024         // supports N <= 65536
#define EPB 4096           // edges per bscatter block
#define SRCMASK 0x03FFFFFF
#define BP1_N (8 * 7 * 64 * 8)   // [ct][ks][lane][j] fragment-packed W1 (K=224 pad)
#define BP2_N (8 * 4 * 64 * 8)   // fragment-packed [W2l|W2r] (K=128)

typedef unsigned short ushort_t;
typedef unsigned int uint_t;
typedef _Float16 f16x8 __attribute__((ext_vector_type(8)));
typedef _Float16 h2 __attribute__((ext_vector_type(2)));
typedef __attribute__((ext_vector_type(4))) float f32x4;

__device__ inline void atomicMaxF(float* addr, float val) {
    if (val >= 0.f) atomicMax((int*)addr, __float_as_int(val));
    else            atomicMin((unsigned int*)addr, __float_as_uint(val));
}

__device__ inline ushort_t f2h_bits(float f) {
    return __builtin_bit_cast(ushort_t, (_Float16)f);
}

__device__ inline h2 u_as_h2(uint_t u) {
    return __builtin_bit_cast(h2, u);
}

// ---- init: zero bcnt + out=-inf -----------------------------------------
__global__ void init0_kernel(int* bcnt, int nbk, float* out, int n) {
    int i = blockIdx.x * 256 + threadIdx.x;
    if (i < nbk) bcnt[i] = 0;
    if (i < n) out[i] = -__builtin_inff();
}

// ---- setup: bhist (first nebl blocks) + prep f16 (rest) -----------------
__global__ __launch_bounds__(256) void setup_kernel(
        const int* __restrict__ dst, int* __restrict__ bcnt, int E, int nbk, int nebl,
        const float* __restrict__ x, const float* __restrict__ votes,
        const float* __restrict__ W1l, const float* __restrict__ W1r,
        const float* __restrict__ W2l, const float* __restrict__ W2r,
        ushort_t* __restrict__ xb, ushort_t* __restrict__ bp1,
        ushort_t* __restrict__ bp2, int N) {
    __shared__ int lh[MAXBK];
    if ((int)blockIdx.x < nebl) {
        for (int i = threadIdx.x; i < nbk; i += 256) lh[i] = 0;
        __syncthreads();
        int base = blockIdx.x * EPB;
        int end = min(base + EPB, E);
        for (int k = base + threadIdx.x; k < end; k += 256)
            atomicAdd(&lh[dst[k] >> BSH], 1);
        __syncthreads();
        for (int i = threadIdx.x; i < nbk; i += 256)
            if (lh[i] > 0) atomicAdd(&bcnt[i], lh[i]);
        return;
    }
    int idx = ((int)blockIdx.x - nebl) * 256 + threadIdx.x;
    if (idx < N * IN_F) {
        int n = idx / IN_F, f = idx - n * IN_F;
        float v = (f < XD) ? x[n * XD + f] : votes[n];
        xb[idx] = f2h_bits(v);
    }
    if (idx < BP1_N) {
        int j = idx & 7;
        int lane = (idx >> 3) & 63;
        int rest = idx >> 9;
        int ks = rest % 7;
        int ct = rest / 7;
        int k = ks * 32 + (lane >> 4) * 8 + j;
        int col = ct * 16 + (lane & 15);
        float v = 0.f;
        if (k < IN_F) v = W1l[k * HID + col];
        else if (k < 2 * IN_F) v = W1r[(k - IN_F) * HID + col];
        bp1[idx] = f2h_bits(v);
    }
    int i2 = idx - BP1_N;
    if (i2 >= 0 && i2 < BP2_N) {
        int j = i2 & 7;
        int lane = (i2 >> 3) & 63;
        int ks = (i2 >> 9) & 3;
        int ct = i2 >> 11;
        int k = ks * 32 + (lane >> 4) * 8 + j;
        int col = ct * 16 + (lane & 15);
        float v = (col < OUTD) ? W2l[k * OUTD + col] : W2r[k * OUTD + (col - OUTD)];
        bp2[i2] = f2h_bits(v);
    }
}

// ---- A2: exclusive scan of bucket counts (one wave) ---------------------
__global__ __launch_bounds__(64) void bscan_kernel(const int* __restrict__ bcnt,
                                                   int* __restrict__ bbase,
                                                   int* __restrict__ brsv,
                                                   int* __restrict__ row_start,
                                                   int nbk, int N, int E) {
    int lane = threadIdx.x;
    int carry = 0;
    for (int b = 0; b < nbk; b += 64) {
        int i = b + lane;
        int orig = (i < nbk) ? bcnt[i] : 0;
        int v = orig;
#pragma unroll
        for (int d = 1; d < 64; d <<= 1) {
            int t = __shfl_up(v, d);
            if (lane >= d) v += t;
        }
        if (i < nbk) {
            int ex = carry + v - orig;
            bbase[i] = ex;
            brsv[i] = ex;
        }
        carry += __shfl(v, 63);
    }
    if (lane == 0) {
        bbase[nbk] = E;
        row_start[N] = E;
    }
}

// ---- A3: scatter edges into bucket-grouped ebuf (packed uint) -----------
__global__ __launch_bounds__(256) void bscatter_kernel(const int* __restrict__ src,
                                                       const int* __restrict__ dst,
                                                       int* __restrict__ brsv,
                                                       uint_t* __restrict__ ebuf,
                                                       int E, int nbk) {
    __shared__ int lh[MAXBK];
    __shared__ int lofs[MAXBK];
    for (int i = threadIdx.x; i < nbk; i += 256) lh[i] = 0;
    __syncthreads();
    int base = blockIdx.x * EPB;
    int end = min(base + EPB, E);
    for (int k = base + threadIdx.x; k < end; k += 256)
        atomicAdd(&lh[dst[k] >> BSH], 1);
    __syncthreads();
    for (int i = threadIdx.x; i < nbk; i += 256)
        if (lh[i] > 0) lofs[i] = atomicAdd(&brsv[i], lh[i]);
    __syncthreads();
    for (int k = base + threadIdx.x; k < end; k += 256) {
        int d = dst[k];
        int pos = atomicAdd(&lofs[d >> BSH], 1);
        ebuf[pos] = (uint_t)src[k] | ((uint_t)(d & (BNODES - 1)) << 26);
    }
}

// ---- B: per-bucket CSR build (row_start + sorted_src) -------------------
__global__ __launch_bounds__(256) void bbuild_kernel(const uint_t* __restrict__ ebuf,
                                                     const int* __restrict__ bbase,
                                                     int* __restrict__ row_start,
                                                     int* __restrict__ sorted_src,
                                                     int N) {
    __shared__ int nh[BNODES];
    __shared__ int cur[BNODES];
    int b = blockIdx.x;
    int e0 = bbase[b], e1 = bbase[b + 1];
    int nlo = b << BSH;
    int nloc = min(BNODES, N - nlo);
    if (threadIdx.x < BNODES) nh[threadIdx.x] = 0;
    __syncthreads();
    for (int k = e0 + threadIdx.x; k < e1; k += 256)
        atomicAdd(&nh[ebuf[k] >> 26], 1);
    __syncthreads();
    if (threadIdx.x < 64) {
        int lane = threadIdx.x;
        int orig = nh[lane];
        int v = orig;
#pragma unroll
        for (int d = 1; d < 64; d <<= 1) {
            int t = __shfl_up(v, d);
            if (lane >= d) v += t;
        }
        int ex = e0 + v - orig;
        cur[lane] = ex;
        if (lane < nloc) row_start[nlo + lane] = ex;
    }
    __syncthreads();
    for (int k = e0 + threadIdx.x; k < e1; k += 256) {
        uint_t e = ebuf[k];
        int pos = atomicAdd(&cur[e >> 26], 1);
        sorted_src[pos] = (int)(e & SRCMASK);
    }
}

// ---- fused: gather-mean (pk_add_f16, into LDS) + MFMA f16 dense x2 ------
// h1 = relu([agg|h0] @ [W1l;W1r] + b1);  [u|vb] = h1 @ [W2l|W2r] (+b2 on vb)
#define T1_M 32
#define A_STRIDE_US 232
#define A_STRIDE_U  116
#define H1_STRIDE_US 136
__global__ __launch_bounds__(256) void fused1_kernel(
        const ushort_t* __restrict__ xb,
        const int* __restrict__ row_start, const int* __restrict__ sorted_src,
        const ushort_t* __restrict__ bp1, const ushort_t* __restrict__ bp2,
        const float* __restrict__ b1, const float* __restrict__ b2,
        ushort_t* __restrict__ ub, float* __restrict__ vvb, int N) {
    __shared__ uint_t smem[T1_M * A_STRIDE_U];      // 14848 B
    __shared__ int rsh[T1_M + 1];
    int n0 = blockIdx.x * T1_M;
    const uint_t* xbu = (const uint_t*)xb;

    for (int i = threadIdx.x; i < T1_M * 54; i += 256) {
        int m = i / 54, c = i - m * 54;
        int n = n0 + m;
        smem[m * A_STRIDE_U + 54 + c] = (n < N) ? xbu[n * 54 + c] : 0u;
    }
    for (int i = threadIdx.x; i < T1_M * 4; i += 256) {
        int m = i >> 2, c = i & 3;
        smem[m * A_STRIDE_U + 108 + c] = 0u;
    }
    if (threadIdx.x <= T1_M) {
        int n = n0 + threadIdx.x;
        rsh[threadIdx.x] = row_start[min(n, N)];
    }
    __syncthreads();

    int lane = threadIdx.x & 63;
    int wid  = threadIdx.x >> 6;
    int h  = lane >> 5;
    int l2 = lane & 31;

    // phase B: gather-mean (packed f16 accumulate)
    int mq8 = wid * 8;
    for (int it = 0; it < 8; ++it) {
        int m = mq8 + it;
        int rs = rsh[m], re = rsh[m + 1];
        h2 c01 = {(_Float16)0.f, (_Float16)0.f};
        h2 c23 = {(_Float16)0.f, (_Float16)0.f};
        for (int k0 = rs; k0 < re; k0 += 64) {
            int cnt = min(64, re - k0);
            int sl = sorted_src[k0 + min(lane, cnt - 1)];
            int t = 0;
            for (; t + 8 <= cnt; t += 8) {
                int s0 = __shfl(sl, t + h);
                int s1 = __shfl(sl, t + 2 + h);
                int s2 = __shfl(sl, t + 4 + h);
                int s3 = __shfl(sl, t + 6 + h);
                if (l2 < 27) {
                    uint2 w0 = *(const uint2*)(xb + s0 * IN_F + 4 * l2);
                    uint2 w1 = *(const uint2*)(xb + s1 * IN_F + 4 * l2);
                    uint2 w2 = *(const uint2*)(xb + s2 * IN_F + 4 * l2);
                    uint2 w3 = *(const uint2*)(xb + s3 * IN_F + 4 * l2);
                    c01 += u_as_h2(w0.x); c23 += u_as_h2(w0.y);
                    c01 += u_as_h2(w1.x); c23 += u_as_h2(w1.y);
                    c01 += u_as_h2(w2.x); c23 += u_as_h2(w2.y);
                    c01 += u_as_h2(w3.x); c23 += u_as_h2(w3.y);
                }
            }
            for (; t < cnt; t += 2) {
                int tt = min(t + h, cnt - 1);
                int s = __shfl(sl, tt);
                if (t + h < cnt && l2 < 27) {
                    uint2 w = *(const uint2*)(xb + s * IN_F + 4 * l2);
                    c01 += u_as_h2(w.x);
                    c23 += u_as_h2(w.y);
                }
            }
        }
        float a0 = (float)c01[0], a1 = (float)c01[1];
        float a2 = (float)c23[0], a3 = (float)c23[1];
        a0 += __shfl_xor(a0, 32);
        a1 += __shfl_xor(a1, 32);
        a2 += __shfl_xor(a2, 32);
        a3 += __shfl_xor(a3, 32);
        int node = n0 + m;
        if (node < N && l2 < 27) {
            float inv = 1.f / fmaxf((float)(re - rs), 1.f);
            ushort4 p;
            p.x = f2h_bits(a0 * inv);
            p.y = f2h_bits(a1 * inv);
            p.z = f2h_bits(a2 * inv);
            p.w = f2h_bits(a3 * inv);
            *(ushort4*)((ushort_t*)smem + m * A_STRIDE_US + 4 * l2) = p;
        }
    }
    __syncthreads();

    // phase C: MFMA layer 1 (f16)
    int wrow = (wid & 1) << 4;
    int wcol = (wid >> 1) << 6;
    int arow = wrow + (lane & 15);
    int akoff = (lane >> 4) * 8;
    const ushort_t* sA = (const ushort_t*)smem;
    const f16x8* bp1v = (const f16x8*)bp1;

    f32x4 acc0 = {}, acc1 = {}, acc2_ = {}, acc3 = {};
    int ct0 = wcol >> 4;
#pragma unroll
    for (int ks = 0; ks < 7; ++ks) {
        f16x8 af = *(const f16x8*)(sA + arow * A_STRIDE_US + ks * 32 + akoff);
        f16x8 bf0 = bp1v[((ct0 + 0) * 7 + ks) * 64 + lane];
        f16x8 bf1 = bp1v[((ct0 + 1) * 7 + ks) * 64 + lane];
        f16x8 bf2 = bp1v[((ct0 + 2) * 7 + ks) * 64 + lane];
        f16x8 bf3 = bp1v[((ct0 + 3) * 7 + ks) * 64 + lane];
        acc0 = __builtin_amdgcn_mfma_f32_16x16x32_f16(af, bf0, acc0, 0, 0, 0);
        acc1 = __builtin_amdgcn_mfma_f32_16x16x32_f16(af, bf1, acc1, 0, 0, 0);
        acc2_ = __builtin_amdgcn_mfma_f32_16x16x32_f16(af, bf2, acc2_, 0, 0, 0);
        acc3 = __builtin_amdgcn_mfma_f32_16x16x32_f16(af, bf3, acc3, 0, 0, 0);
    }

    __syncthreads();
    ushort_t* sh1 = (ushort_t*)smem;
    {
        int colb = wcol + (lane & 15);
        int rowb = wrow + ((lane >> 4) << 2);
#pragma unroll
        for (int t = 0; t < 4; ++t) {
            f32x4 a = (t == 0) ? acc0 : (t == 1) ? acc1 : (t == 2) ? acc2_ : acc3;
            int col = colb + t * 16;
            float bj = b1[col];
#pragma unroll
            for (int r = 0; r < 4; ++r)
                sh1[(rowb + r) * H1_STRIDE_US + col] = f2h_bits(fmaxf(a[r] + bj, 0.f));
        }
    }
    __syncthreads();

    // phase D: MFMA layer 2 ([u|v+b2])
    const f16x8* bp2v = (const f16x8*)bp2;
    f32x4 dcc0 = {}, dcc1 = {}, dcc2 = {}, dcc3 = {};
#pragma unroll
    for (int ks = 0; ks < 4; ++ks) {
        f16x8 af = *(const f16x8*)(sh1 + arow * H1_STRIDE_US + ks * 32 + akoff);
        f16x8 bf0 = bp2v[((ct0 + 0) * 4 + ks) * 64 + lane];
        f16x8 bf1 = bp2v[((ct0 + 1) * 4 + ks) * 64 + lane];
        f16x8 bf2 = bp2v[((ct0 + 2) * 4 + ks) * 64 + lane];
        f16x8 bf3 = bp2v[((ct0 + 3) * 4 + ks) * 64 + lane];
        dcc0 = __builtin_amdgcn_mfma_f32_16x16x32_f16(af, bf0, dcc0, 0, 0, 0);
        dcc1 = __builtin_amdgcn_mfma_f32_16x16x32_f16(af, bf1, dcc1, 0, 0, 0);
        dcc2 = __builtin_amdgcn_mfma_f32_16x16x32_f16(af, bf2, dcc2, 0, 0, 0);
        dcc3 = __builtin_amdgcn_mfma_f32_16x16x32_f16(af, bf3, dcc3, 0, 0, 0);
    }

    {
        int colb = wcol + (lane & 15);
        int rowb = wrow + ((lane >> 4) << 2);
#pragma unroll
        for (int t = 0; t < 4; ++t) {
            f32x4 a = (t == 0) ? dcc0 : (t == 1) ? dcc1 : (t == 2) ? dcc2 : dcc3;
            int col = colb + t * 16;
#pragma unroll
            for (int r = 0; r < 4; ++r) {
                int n = n0 + rowb + r;
                if (n < N) {
                    if (col < OUTD) {
                        ub[(n << 6) + col] = f2h_bits(a[r]);
                    } else {
                        vvb[(n << 6) + (col - OUTD)] = a[r] + b2[col - OUTD];
                    }
                }
            }
        }
    }
}

// ---- gatherf: aggu(gather-mean of u) + vvb, run-length segment-max ------
// block = 4 waves; wave handles 4 consecutive nodes (TLP-heavy).
#define GF_NPW 4
#define GF_NODES (4 * GF_NPW)
__global__ __launch_bounds__(256) void gatherf_kernel(
        const ushort_t* __restrict__ ub,
        const int* __restrict__ row_start, const int* __restrict__ sorted_src,
        const float* __restrict__ vvb, const int* __restrict__ batch,
        float* __restrict__ out, int N) {
    int lane = threadIdx.x & 63;
    int wid = threadIdx.x >> 6;
    int nbase = blockIdx.x * GF_NODES + wid * GF_NPW;
    int g4 = lane >> 4;
    int l4 = lane & 15;
    int curg = -1;
    float m0 = 0.f, m1 = 0.f, m2 = 0.f, m3 = 0.f;
    for (int it = 0; it < GF_NPW; ++it) {
        int node = nbase + it;
        if (node >= N) break;
        int rs = row_start[node], re = row_start[node + 1];
        h2 c01 = {(_Float16)0.f, (_Float16)0.f};
        h2 c23 = {(_Float16)0.f, (_Float16)0.f};
        for (int k0 = rs; k0 < re; k0 += 64) {
            int cnt = min(64, re - k0);
            int sl = sorted_src[k0 + min(lane, cnt - 1)];
            int t = 0;
            for (; t + 8 <= cnt; t += 8) {
                int s0 = __shfl(sl, t + g4);
                int s1 = __shfl(sl, t + 4 + g4);
                uint2 w0 = *(const uint2*)(ub + (s0 << 6) + 4 * l4);
                uint2 w1 = *(const uint2*)(ub + (s1 << 6) + 4 * l4);
                c01 += u_as_h2(w0.x); c23 += u_as_h2(w0.y);
                c01 += u_as_h2(w1.x); c23 += u_as_h2(w1.y);
            }
            for (; t < cnt; t += 4) {
                int tt = min(t + g4, cnt - 1);
                int s = __shfl(sl, tt);
                if (t + g4 < cnt) {
                    uint2 w = *(const uint2*)(ub + (s << 6) + 4 * l4);
                    c01 += u_as_h2(w.x);
                    c23 += u_as_h2(w.y);
                }
            }
        }
        float a0 = (float)c01[0], a1 = (float)c01[1];
        float a2 = (float)c23[0], a3 = (float)c23[1];
        a0 += __shfl_xor(a0, 16); a0 += __shfl_xor(a0, 32);
        a1 += __shfl_xor(a1, 16); a1 += __shfl_xor(a1, 32);
        a2 += __shfl_xor(a2, 16); a2 += __shfl_xor(a2, 32);
        a3 += __shfl_xor(a3, 16); a3 += __shfl_xor(a3, 32);
        if (lane < 16) {
            float inv = 1.f / fmaxf((float)(re - rs), 1.f);
            float4 vb = *(const float4*)(vvb + (node << 6) + 4 * l4);
            float h0v = a0 * inv + vb.x;
            float h1v = a1 * inv + vb.y;
            float h2v = a2 * inv + vb.z;
            float h3v = a3 * inv + vb.w;
            int g = batch[node];
            if (g != curg) {
                if (curg >= 0) {
                    float* o = out + (curg << 6) + 4 * l4;
                    atomicMaxF(o + 0, m0);
                    atomicMaxF(o + 1, m1);
                    atomicMaxF(o + 2, m2);
                    atomicMaxF(o + 3, m3);
                }
                curg = g;
                m0 = h0v; m1 = h1v; m2 = h2v; m3 = h3v;
            } else {
                m0 = fmaxf(m0, h0v);
                m1 = fmaxf(m1, h1v);
                m2 = fmaxf(m2, h2v);
                m3 = fmaxf(m3, h3v);
            }
        }
    }
    if (lane < 16 && curg >= 0) {
        float* o = out + (curg << 6) + 4 * l4;
        atomicMaxF(o + 0, m0);
        atomicMaxF(o + 1, m1);
        atomicMaxF(o + 2, m2);
        atomicMaxF(o + 3, m3);
    }
}

static inline size_t align256(size_t v) { return (v + 255) & ~(size_t)255; }

extern "C" void kernel_launch(void* const* d_in, const int* in_sizes, int n_in,
                              void* d_out, int out_size, void* d_ws, size_t ws_size,
                              hipStream_t stream) {
    const float* x     = (const float*)d_in[0];
    const float* votes = (const float*)d_in[1];
    const int*   eidx  = (const int*)d_in[2];
    const int*   batch = (const int*)d_in[3];
    const float* W1l   = (const float*)d_in[4];
    const float* b1    = (const float*)d_in[5];
    const float* W1r   = (const float*)d_in[6];
    const float* W2l   = (const float*)d_in[7];
    const float* b2    = (const float*)d_in[8];
    const float* W2r   = (const float*)d_in[9];
    float* out = (float*)d_out;

    const int N = in_sizes[1];
    const int E = in_sizes[2] / 2;
    const int* src = eidx;
    const int* dst = eidx + E;
    const int nbk = (N + BNODES - 1) >> BSH;   // 782 for N=50000

    char* ws = (char*)d_ws;
    size_t off = 0;
    int* bcnt       = (int*)(ws + off); off = align256(off + (size_t)nbk * 4);
    int* bbase      = (int*)(ws + off); off = align256(off + (size_t)(nbk + 1) * 4);
    int* brsv       = (int*)(ws + off); off = align256(off + (size_t)nbk * 4);
    int* row_start  = (int*)(ws + off); off = align256(off + (size_t)(N + 1) * 4);
    uint_t* ebuf    = (uint_t*)(ws + off); off = align256(off + (size_t)E * 4);
    int* sorted_src = (int*)(ws + off); off = align256(off + (size_t)E * 4);
    ushort_t* xb    = (ushort_t*)(ws + off); off = align256(off + (size_t)N * IN_F * 2);
    ushort_t* ub    = (ushort_t*)(ws + off); off = align256(off + (size_t)N * OUTD * 2);
    float* vvb      = (float*)(ws + off); off = align256(off + (size_t)N * OUTD * 4);
    ushort_t* bp1   = (ushort_t*)(ws + off); off = align256(off + (size_t)BP1_N * 2);
    ushort_t* bp2   = (ushort_t*)(ws + off); off = align256(off + (size_t)BP2_N * 2);

    // init (bcnt zero + out=-inf)
    {
        int mx = max(nbk, out_size);
        init0_kernel<<<(mx + 255) / 256, 256, 0, stream>>>(bcnt, nbk, out, out_size);
    }

    // setup: bhist + xb/bp1/bp2 conversions in one launch
    int nebl = (E + EPB - 1) / EPB;
    int prep_blocks = (N * IN_F + 255) / 256;
    setup_kernel<<<nebl + prep_blocks, 256, 0, stream>>>(dst, bcnt, E, nbk, nebl,
                                                         x, votes, W1l, W1r, W2l, W2r,
                                                         xb, bp1, bp2, N);

    // CSR
    bscan_kernel<<<1, 64, 0, stream>>>(bcnt, bbase, brsv, row_start, nbk, N, E);
    bscatter_kernel<<<nebl, 256, 0, stream>>>(src, dst, brsv, ebuf, E, nbk);
    bbuild_kernel<<<nbk, 256, 0, stream>>>(ebuf, bbase, row_start, sorted_src, N);

    // fused gather + both dense matmuls via MFMA f16 (agg + h1 stay in LDS)
    fused1_kernel<<<(N + T1_M - 1) / T1_M, 256, 0, stream>>>(xb, row_start, sorted_src,
                                                             bp1, bp2, b1, b2, ub, vvb, N);
    // layer-2 aggregate fused with segment-max
    gatherf_kernel<<<(N + GF_NODES - 1) / GF_NODES, 256, 0, stream>>>(
        ub, row_start, sorted_src, vvb, batch, out, N);
}

// Round 17
// 131.959 us; speedup vs baseline: 1.3530x; 1.3530x over previous
//
#include <hip/hip_runtime.h>
#include <hip/hip_bf16.h>

#define IN_F 108   // concat(x[107], votes[1])
#define XD   107
#define HID  128
#define OUTD 64
#define SEG_NODES 64
#define BSH 6              // bucket = dst >> 6 (64 nodes per bucket)
#define BNODES 64
#define MAXBK 1024         // supports N <= 65536
#define EPB 4096           // edges per bscatter block
#define SRCMASK 0x03FFFFFF
#define BP1_N (8 * 7 * 64 * 8)   // [ct][ks][lane][j] fragment-packed W1 (K=224 pad)
#define BP2_N (8 * 4 * 64 * 8)   // fragment-packed [W2l|W2r] (K=128)

typedef unsigned short ushort_t;
typedef unsigned int uint_t;
typedef __attribute__((ext_vector_type(8))) short bf16x8;
typedef __attribute__((ext_vector_type(4))) float f32x4;

__device__ inline void atomicMaxF(float* addr, float val) {
    if (val >= 0.f) atomicMax((int*)addr, __float_as_int(val));
    else            atomicMin((unsigned int*)addr, __float_as_uint(val));
}

__device__ inline ushort_t f2bf(float f) {
    uint_t b = __float_as_uint(f);
    return (ushort_t)((b + 0x7fffu + ((b >> 16) & 1u)) >> 16);   // RNE
}

// ---- init: zero bcnt + out=-inf -----------------------------------------
__global__ void init0_kernel(int* bcnt, int nbk, float* out, int n) {
    int i = blockIdx.x * 256 + threadIdx.x;
    if (i < nbk) bcnt[i] = 0;
    if (i < n) out[i] = -__builtin_inff();
}

// ---- setup: bhist (first nebl blocks) + prep (rest) ---------------------
__global__ __launch_bounds__(256) void setup_kernel(
        const int* __restrict__ dst, int* __restrict__ bcnt, int E, int nbk, int nebl,
        const float* __restrict__ x, const float* __restrict__ votes,
        const float* __restrict__ W1l, const float* __restrict__ W1r,
        const float* __restrict__ W2l, const float* __restrict__ W2r,
        ushort_t* __restrict__ xb, ushort_t* __restrict__ bp1,
        ushort_t* __restrict__ bp2, int N) {
    __shared__ int lh[MAXBK];
    if ((int)blockIdx.x < nebl) {
        for (int i = threadIdx.x; i < nbk; i += 256) lh[i] = 0;
        __syncthreads();
        int base = blockIdx.x * EPB;
        int end = min(base + EPB, E);
        for (int k = base + threadIdx.x; k < end; k += 256)
            atomicAdd(&lh[dst[k] >> BSH], 1);
        __syncthreads();
        for (int i = threadIdx.x; i < nbk; i += 256)
            if (lh[i] > 0) atomicAdd(&bcnt[i], lh[i]);
        return;
    }
    int idx = ((int)blockIdx.x - nebl) * 256 + threadIdx.x;
    if (idx < N * IN_F) {
        int n = idx / IN_F, f = idx - n * IN_F;
        float v = (f < XD) ? x[n * XD + f] : votes[n];
        xb[idx] = f2bf(v);
    }
    if (idx < BP1_N) {
        int j = idx & 7;
        int lane = (idx >> 3) & 63;
        int rest = idx >> 9;
        int ks = rest % 7;
        int ct = rest / 7;
        int k = ks * 32 + (lane >> 4) * 8 + j;
        int col = ct * 16 + (lane & 15);
        float v = 0.f;
        if (k < IN_F) v = W1l[k * HID + col];
        else if (k < 2 * IN_F) v = W1r[(k - IN_F) * HID + col];
        bp1[idx] = f2bf(v);
    }
    int i2 = idx - BP1_N;
    if (i2 >= 0 && i2 < BP2_N) {
        int j = i2 & 7;
        int lane = (i2 >> 3) & 63;
        int ks = (i2 >> 9) & 3;
        int ct = i2 >> 11;
        int k = ks * 32 + (lane >> 4) * 8 + j;
        int col = ct * 16 + (lane & 15);
        float v = (col < OUTD) ? W2l[k * OUTD + col] : W2r[k * OUTD + (col - OUTD)];
        bp2[i2] = f2bf(v);
    }
}

// ---- A2: exclusive scan of bucket counts (one wave) ---------------------
__global__ __launch_bounds__(64) void bscan_kernel(const int* __restrict__ bcnt,
                                                   int* __restrict__ bbase,
                                                   int* __restrict__ brsv,
                                                   int* __restrict__ row_start,
                                                   int nbk, int N, int E) {
    int lane = threadIdx.x;
    int carry = 0;
    for (int b = 0; b < nbk; b += 64) {
        int i = b + lane;
        int orig = (i < nbk) ? bcnt[i] : 0;
        int v = orig;
#pragma unroll
        for (int d = 1; d < 64; d <<= 1) {
            int t = __shfl_up(v, d);
            if (lane >= d) v += t;
        }
        if (i < nbk) {
            int ex = carry + v - orig;
            bbase[i] = ex;
            brsv[i] = ex;
        }
        carry += __shfl(v, 63);
    }
    if (lane == 0) {
        bbase[nbk] = E;
        row_start[N] = E;
    }
}

// ---- A3: scatter edges into bucket-grouped ebuf (packed uint) -----------
__global__ __launch_bounds__(256) void bscatter_kernel(const int* __restrict__ src,
                                                       const int* __restrict__ dst,
                                                       int* __restrict__ brsv,
                                                       uint_t* __restrict__ ebuf,
                                                       int E, int nbk) {
    __shared__ int lh[MAXBK];
    __shared__ int lofs[MAXBK];
    for (int i = threadIdx.x; i < nbk; i += 256) lh[i] = 0;
    __syncthreads();
    int base = blockIdx.x * EPB;
    int end = min(base + EPB, E);
    for (int k = base + threadIdx.x; k < end; k += 256)
        atomicAdd(&lh[dst[k] >> BSH], 1);
    __syncthreads();
    for (int i = threadIdx.x; i < nbk; i += 256)
        if (lh[i] > 0) lofs[i] = atomicAdd(&brsv[i], lh[i]);
    __syncthreads();
    for (int k = base + threadIdx.x; k < end; k += 256) {
        int d = dst[k];
        int pos = atomicAdd(&lofs[d >> BSH], 1);
        ebuf[pos] = (uint_t)src[k] | ((uint_t)(d & (BNODES - 1)) << 26);
    }
}

// ---- B: per-bucket CSR build (row_start + sorted_src) -------------------
__global__ __launch_bounds__(256) void bbuild_kernel(const uint_t* __restrict__ ebuf,
                                                     const int* __restrict__ bbase,
                                                     int* __restrict__ row_start,
                                                     int* __restrict__ sorted_src,
                                                     int N) {
    __shared__ int nh[BNODES];
    __shared__ int cur[BNODES];
    int b = blockIdx.x;
    int e0 = bbase[b], e1 = bbase[b + 1];
    int nlo = b << BSH;
    int nloc = min(BNODES, N - nlo);
    if (threadIdx.x < BNODES) nh[threadIdx.x] = 0;
    __syncthreads();
    for (int k = e0 + threadIdx.x; k < e1; k += 256)
        atomicAdd(&nh[ebuf[k] >> 26], 1);
    __syncthreads();
    if (threadIdx.x < 64) {
        int lane = threadIdx.x;
        int orig = nh[lane];
        int v = orig;
#pragma unroll
        for (int d = 1; d < 64; d <<= 1) {
            int t = __shfl_up(v, d);
            if (lane >= d) v += t;
        }
        int ex = e0 + v - orig;
        cur[lane] = ex;
        if (lane < nloc) row_start[nlo + lane] = ex;
    }
    __syncthreads();
    for (int k = e0 + threadIdx.x; k < e1; k += 256) {
        uint_t e = ebuf[k];
        int pos = atomicAdd(&cur[e >> 26], 1);
        sorted_src[pos] = (int)(e & SRCMASK);
    }
}

// ---- fused: gather-mean (into LDS) + MFMA dense x2 ----------------------
// h1 = relu([agg|h0] @ [W1l;W1r] + b1);  [u|vb] = h1 @ [W2l|W2r] (+b2 on vb)
#define T1_M 32
#define A_STRIDE_US 232
#define A_STRIDE_U  116
#define H1_STRIDE_US 136
__global__ __launch_bounds__(256) void fused1_kernel(
        const ushort_t* __restrict__ xb,
        const int* __restrict__ row_start, const int* __restrict__ sorted_src,
        const ushort_t* __restrict__ bp1, const ushort_t* __restrict__ bp2,
        const float* __restrict__ b1, const float* __restrict__ b2,
        ushort_t* __restrict__ ub, float* __restrict__ vvb, int N) {
    __shared__ uint_t smem[T1_M * A_STRIDE_U];      // 14848 B
    __shared__ int rsh[T1_M + 1];
    int n0 = blockIdx.x * T1_M;
    const uint_t* xbu = (const uint_t*)xb;

    for (int i = threadIdx.x; i < T1_M * 54; i += 256) {
        int m = i / 54, c = i - m * 54;
        int n = n0 + m;
        smem[m * A_STRIDE_U + 54 + c] = (n < N) ? xbu[n * 54 + c] : 0u;
    }
    for (int i = threadIdx.x; i < T1_M * 4; i += 256) {
        int m = i >> 2, c = i & 3;
        smem[m * A_STRIDE_U + 108 + c] = 0u;
    }
    if (threadIdx.x <= T1_M) {
        int n = n0 + threadIdx.x;
        rsh[threadIdx.x] = row_start[min(n, N)];
    }
    __syncthreads();

    int lane = threadIdx.x & 63;
    int wid  = threadIdx.x >> 6;
    int h  = lane >> 5;
    int l2 = lane & 31;

    // phase B: gather-mean for this wave's 8 nodes -> LDS agg region
    int mq8 = wid * 8;
    for (int it = 0; it < 8; ++it) {
        int m = mq8 + it;
        int rs = rsh[m], re = rsh[m + 1];
        float a0 = 0.f, a1 = 0.f, a2 = 0.f, a3 = 0.f;
        for (int k0 = rs; k0 < re; k0 += 64) {
            int cnt = min(64, re - k0);
            int sl = sorted_src[k0 + min(lane, cnt - 1)];
            int t = 0;
            for (; t + 8 <= cnt; t += 8) {
                int s0 = __shfl(sl, t + h);
                int s1 = __shfl(sl, t + 2 + h);
                int s2 = __shfl(sl, t + 4 + h);
                int s3 = __shfl(sl, t + 6 + h);
                if (l2 < 27) {
                    uint2 w0 = *(const uint2*)(xb + s0 * IN_F + 4 * l2);
                    uint2 w1 = *(const uint2*)(xb + s1 * IN_F + 4 * l2);
                    uint2 w2 = *(const uint2*)(xb + s2 * IN_F + 4 * l2);
                    uint2 w3 = *(const uint2*)(xb + s3 * IN_F + 4 * l2);
                    a0 += __uint_as_float(w0.x << 16) + __uint_as_float(w1.x << 16)
                        + __uint_as_float(w2.x << 16) + __uint_as_float(w3.x << 16);
                    a1 += __uint_as_float(w0.x & 0xffff0000u) + __uint_as_float(w1.x & 0xffff0000u)
                        + __uint_as_float(w2.x & 0xffff0000u) + __uint_as_float(w3.x & 0xffff0000u);
                    a2 += __uint_as_float(w0.y << 16) + __uint_as_float(w1.y << 16)
                        + __uint_as_float(w2.y << 16) + __uint_as_float(w3.y << 16);
                    a3 += __uint_as_float(w0.y & 0xffff0000u) + __uint_as_float(w1.y & 0xffff0000u)
                        + __uint_as_float(w2.y & 0xffff0000u) + __uint_as_float(w3.y & 0xffff0000u);
                }
            }
            for (; t < cnt; t += 2) {
                int tt = min(t + h, cnt - 1);
                int s = __shfl(sl, tt);
                if (t + h < cnt && l2 < 27) {
                    uint2 w = *(const uint2*)(xb + s * IN_F + 4 * l2);
                    a0 += __uint_as_float(w.x << 16);
                    a1 += __uint_as_float(w.x & 0xffff0000u);
                    a2 += __uint_as_float(w.y << 16);
                    a3 += __uint_as_float(w.y & 0xffff0000u);
                }
            }
        }
        a0 += __shfl_xor(a0, 32);
        a1 += __shfl_xor(a1, 32);
        a2 += __shfl_xor(a2, 32);
        a3 += __shfl_xor(a3, 32);
        int node = n0 + m;
        if (node < N && l2 < 27) {
            float inv = 1.f / fmaxf((float)(re - rs), 1.f);
            ushort4 p;
            p.x = f2bf(a0 * inv);
            p.y = f2bf(a1 * inv);
            p.z = f2bf(a2 * inv);
            p.w = f2bf(a3 * inv);
            *(ushort4*)((ushort_t*)smem + m * A_STRIDE_US + 4 * l2) = p;
        }
    }
    __syncthreads();

    // phase C: MFMA layer 1
    int wrow = (wid & 1) << 4;
    int wcol = (wid >> 1) << 6;
    int arow = wrow + (lane & 15);
    int akoff = (lane >> 4) * 8;
    const ushort_t* sA = (const ushort_t*)smem;
    const bf16x8* bp1v = (const bf16x8*)bp1;

    f32x4 acc0 = {}, acc1 = {}, acc2_ = {}, acc3 = {};
    int ct0 = wcol >> 4;
#pragma unroll
    for (int ks = 0; ks < 7; ++ks) {
        bf16x8 af = *(const bf16x8*)(sA + arow * A_STRIDE_US + ks * 32 + akoff);
        bf16x8 bf0 = bp1v[((ct0 + 0) * 7 + ks) * 64 + lane];
        bf16x8 bf1 = bp1v[((ct0 + 1) * 7 + ks) * 64 + lane];
        bf16x8 bf2 = bp1v[((ct0 + 2) * 7 + ks) * 64 + lane];
        bf16x8 bf3 = bp1v[((ct0 + 3) * 7 + ks) * 64 + lane];
        acc0 = __builtin_amdgcn_mfma_f32_16x16x32_bf16(af, bf0, acc0, 0, 0, 0);
        acc1 = __builtin_amdgcn_mfma_f32_16x16x32_bf16(af, bf1, acc1, 0, 0, 0);
        acc2_ = __builtin_amdgcn_mfma_f32_16x16x32_bf16(af, bf2, acc2_, 0, 0, 0);
        acc3 = __builtin_amdgcn_mfma_f32_16x16x32_bf16(af, bf3, acc3, 0, 0, 0);
    }

    __syncthreads();
    ushort_t* sh1 = (ushort_t*)smem;
    {
        int colb = wcol + (lane & 15);
        int rowb = wrow + ((lane >> 4) << 2);
#pragma unroll
        for (int t = 0; t < 4; ++t) {
            f32x4 a = (t == 0) ? acc0 : (t == 1) ? acc1 : (t == 2) ? acc2_ : acc3;
            int col = colb + t * 16;
            float bj = b1[col];
#pragma unroll
            for (int r = 0; r < 4; ++r)
                sh1[(rowb + r) * H1_STRIDE_US + col] = f2bf(fmaxf(a[r] + bj, 0.f));
        }
    }
    __syncthreads();

    // phase D: MFMA layer 2 ([u|v+b2])
    const bf16x8* bp2v = (const bf16x8*)bp2;
    f32x4 dcc0 = {}, dcc1 = {}, dcc2 = {}, dcc3 = {};
#pragma unroll
    for (int ks = 0; ks < 4; ++ks) {
        bf16x8 af = *(const bf16x8*)(sh1 + arow * H1_STRIDE_US + ks * 32 + akoff);
        bf16x8 bf0 = bp2v[((ct0 + 0) * 4 + ks) * 64 + lane];
        bf16x8 bf1 = bp2v[((ct0 + 1) * 4 + ks) * 64 + lane];
        bf16x8 bf2 = bp2v[((ct0 + 2) * 4 + ks) * 64 + lane];
        bf16x8 bf3 = bp2v[((ct0 + 3) * 4 + ks) * 64 + lane];
        dcc0 = __builtin_amdgcn_mfma_f32_16x16x32_bf16(af, bf0, dcc0, 0, 0, 0);
        dcc1 = __builtin_amdgcn_mfma_f32_16x16x32_bf16(af, bf1, dcc1, 0, 0, 0);
        dcc2 = __builtin_amdgcn_mfma_f32_16x16x32_bf16(af, bf2, dcc2, 0, 0, 0);
        dcc3 = __builtin_amdgcn_mfma_f32_16x16x32_bf16(af, bf3, dcc3, 0, 0, 0);
    }

    {
        int colb = wcol + (lane & 15);
        int rowb = wrow + ((lane >> 4) << 2);
#pragma unroll
        for (int t = 0; t < 4; ++t) {
            f32x4 a = (t == 0) ? dcc0 : (t == 1) ? dcc1 : (t == 2) ? dcc2 : dcc3;
            int col = colb + t * 16;
#pragma unroll
            for (int r = 0; r < 4; ++r) {
                int n = n0 + rowb + r;
                if (n < N) {
                    if (col < OUTD) {
                        ub[(n << 6) + col] = f2bf(a[r]);
                    } else {
                        vvb[(n << 6) + (col - OUTD)] = a[r] + b2[col - OUTD];
                    }
                }
            }
        }
    }
}

// ---- gather-mean of u (bf16, 64 dims; wave per node) --------------------
__global__ __launch_bounds__(256) void gatheru_kernel(
        const ushort_t* __restrict__ ub,
        const int* __restrict__ row_start, const int* __restrict__ sorted_src,
        float* __restrict__ aggu, int N) {
    int node = (blockIdx.x * 256 + threadIdx.x) >> 6;
    int lane = threadIdx.x & 63;
    if (node >= N) return;
    int rs = row_start[node], re = row_start[node + 1];
    int g  = lane >> 4;
    int l4 = lane & 15;
    float a0 = 0.f, a1 = 0.f, a2 = 0.f, a3 = 0.f;
    for (int k0 = rs; k0 < re; k0 += 64) {
        int cnt = min(64, re - k0);
        int sl = sorted_src[k0 + min(lane, cnt - 1)];
        int t = 0;
        for (; t + 8 <= cnt; t += 8) {
            int s0 = __shfl(sl, t + g);
            int s1 = __shfl(sl, t + 4 + g);
            uint2 w0 = *(const uint2*)(ub + (s0 << 6) + 4 * l4);
            uint2 w1 = *(const uint2*)(ub + (s1 << 6) + 4 * l4);
            a0 += __uint_as_float(w0.x << 16) + __uint_as_float(w1.x << 16);
            a1 += __uint_as_float(w0.x & 0xffff0000u) + __uint_as_float(w1.x & 0xffff0000u);
            a2 += __uint_as_float(w0.y << 16) + __uint_as_float(w1.y << 16);
            a3 += __uint_as_float(w0.y & 0xffff0000u) + __uint_as_float(w1.y & 0xffff0000u);
        }
        for (; t < cnt; t += 4) {
            int tt = min(t + g, cnt - 1);
            int s = __shfl(sl, tt);
            if (t + g < cnt) {
                uint2 w = *(const uint2*)(ub + (s << 6) + 4 * l4);
                a0 += __uint_as_float(w.x << 16);
                a1 += __uint_as_float(w.x & 0xffff0000u);
                a2 += __uint_as_float(w.y << 16);
                a3 += __uint_as_float(w.y & 0xffff0000u);
            }
        }
    }
    a0 += __shfl_xor(a0, 16); a0 += __shfl_xor(a0, 32);
    a1 += __shfl_xor(a1, 16); a1 += __shfl_xor(a1, 32);
    a2 += __shfl_xor(a2, 16); a2 += __shfl_xor(a2, 32);
    a3 += __shfl_xor(a3, 16); a3 += __shfl_xor(a3, 32);
    float inv = 1.f / fmaxf((float)(re - rs), 1.f);
    if (lane < 16) {
        *(float4*)(aggu + (node << 6) + 4 * lane) =
            make_float4(a0 * inv, a1 * inv, a2 * inv, a3 * inv);
    }
}

// ---- finalize: h2 = aggu + vvb, then run-length segment-max -------------
__global__ __launch_bounds__(256) void finalize_kernel(
        const float* __restrict__ aggu, const float* __restrict__ vvb,
        const int* __restrict__ batch, float* __restrict__ out, int N) {
    int j  = threadIdx.x & 63;
    int nq = threadIdx.x >> 6;
    int n0 = blockIdx.x * SEG_NODES;
    int curg = -1;
    float curm = -__builtin_inff();
    for (int m = nq; m < SEG_NODES; m += 4) {
        int n = n0 + m;
        if (n >= N) break;
        int g = batch[n];
        float v = aggu[(n << 6) + j] + vvb[(n << 6) + j];
        if (g != curg) {
            if (curg >= 0) atomicMaxF(&out[(curg << 6) + j], curm);
            curg = g;
            curm = v;
        } else {
            curm = fmaxf(curm, v);
        }
    }
    if (curg >= 0) atomicMaxF(&out[(curg << 6) + j], curm);
}

static inline size_t align256(size_t v) { return (v + 255) & ~(size_t)255; }

extern "C" void kernel_launch(void* const* d_in, const int* in_sizes, int n_in,
                              void* d_out, int out_size, void* d_ws, size_t ws_size,
                              hipStream_t stream) {
    const float* x     = (const float*)d_in[0];
    const float* votes = (const float*)d_in[1];
    const int*   eidx  = (const int*)d_in[2];
    const int*   batch = (const int*)d_in[3];
    const float* W1l   = (const float*)d_in[4];
    const float* b1    = (const float*)d_in[5];
    const float* W1r   = (const float*)d_in[6];
    const float* W2l   = (const float*)d_in[7];
    const float* b2    = (const float*)d_in[8];
    const float* W2r   = (const float*)d_in[9];
    float* out = (float*)d_out;

    const int N = in_sizes[1];
    const int E = in_sizes[2] / 2;
    const int* src = eidx;
    const int* dst = eidx + E;
    const int nbk = (N + BNODES - 1) >> BSH;   // 782 for N=50000

    char* ws = (char*)d_ws;
    size_t off = 0;
    int* bcnt       = (int*)(ws + off); off = align256(off + (size_t)nbk * 4);
    int* bbase      = (int*)(ws + off); off = align256(off + (size_t)(nbk + 1) * 4);
    int* brsv       = (int*)(ws + off); off = align256(off + (size_t)nbk * 4);
    int* row_start  = (int*)(ws + off); off = align256(off + (size_t)(N + 1) * 4);
    uint_t* ebuf    = (uint_t*)(ws + off); off = align256(off + (size_t)E * 4);
    int* sorted_src = (int*)(ws + off); off = align256(off + (size_t)E * 4);
    ushort_t* xb    = (ushort_t*)(ws + off); off = align256(off + (size_t)N * IN_F * 2);
    ushort_t* ub    = (ushort_t*)(ws + off); off = align256(off + (size_t)N * OUTD * 2);
    float* vvb      = (float*)(ws + off); off = align256(off + (size_t)N * OUTD * 4);
    float* aggu     = (float*)(ws + off); off = align256(off + (size_t)N * OUTD * 4);
    ushort_t* bp1   = (ushort_t*)(ws + off); off = align256(off + (size_t)BP1_N * 2);
    ushort_t* bp2   = (ushort_t*)(ws + off); off = align256(off + (size_t)BP2_N * 2);

    // init (bcnt zero + out=-inf)
    {
        int mx = max(nbk, out_size);
        init0_kernel<<<(mx + 255) / 256, 256, 0, stream>>>(bcnt, nbk, out, out_size);
    }

    // setup: bhist + xb/bp1/bp2 conversions in one launch
    int nebl = (E + EPB - 1) / EPB;
    int prep_blocks = (N * IN_F + 255) / 256;
    setup_kernel<<<nebl + prep_blocks, 256, 0, stream>>>(dst, bcnt, E, nbk, nebl,
                                                         x, votes, W1l, W1r, W2l, W2r,
                                                         xb, bp1, bp2, N);

    // CSR
    bscan_kernel<<<1, 64, 0, stream>>>(bcnt, bbase, brsv, row_start, nbk, N, E);
    bscatter_kernel<<<nebl, 256, 0, stream>>>(src, dst, brsv, ebuf, E, nbk);
    bbuild_kernel<<<nbk, 256, 0, stream>>>(ebuf, bbase, row_start, sorted_src, N);

    // fused gather + both dense matmuls via MFMA (agg + h1 stay in LDS)
    fused1_kernel<<<(N + T1_M - 1) / T1_M, 256, 0, stream>>>(xb, row_start, sorted_src,
                                                             bp1, bp2, b1, b2, ub, vvb, N);
    // layer-2 aggregate (wave per node)
    gatheru_kernel<<<(N + 3) / 4, 256, 0, stream>>>(ub, row_start, sorted_src, aggu, N);

    // h2 = aggu + vvb, fused with segment-max
    finalize_kernel<<<(N + SEG_NODES - 1) / SEG_NODES, 256, 0, stream>>>(
        aggu, vvb, batch, out, N);
}

// Round 18
// 129.736 us; speedup vs baseline: 1.3762x; 1.0171x over previous
//
#include <hip/hip_runtime.h>
#include <hip/hip_bf16.h>

#define IN_F 108   // concat(x[107], votes[1])
#define XD   107
#define HID  128
#define OUTD 64
#define SEG_NODES 64
#define BSH 6              // bucket = dst >> 6 (64 nodes per bucket)
#define BNODES 64
#define MAXBK 1024         // supports N <= 65536
#define EPB 4096           // edges per bscatter block
#define SRCMASK 0x03FFFFFF
#define XQ_U 27            // uints per fp8 row (108 fp8 bytes)
#define BP1_N (8 * 7 * 64 * 8)   // [ct][ks][lane][j] fragment-packed W1 (K=224 pad)
#define BP2_N (8 * 4 * 64 * 8)   // fragment-packed [W2l|W2r] (K=128)

typedef unsigned short ushort_t;
typedef unsigned int uint_t;
typedef __attribute__((ext_vector_type(8))) short bf16x8;
typedef __attribute__((ext_vector_type(4))) float f32x4;
typedef __attribute__((ext_vector_type(2))) float f32x2;

__device__ inline void atomicMaxF(float* addr, float val) {
    if (val >= 0.f) atomicMax((int*)addr, __float_as_int(val));
    else            atomicMin((unsigned int*)addr, __float_as_uint(val));
}

__device__ inline ushort_t f2bf(float f) {
    uint_t b = __float_as_uint(f);
    return (ushort_t)((b + 0x7fffu + ((b >> 16) & 1u)) >> 16);   // RNE
}

// ---- init: zero bcnt + out=-inf -----------------------------------------
__global__ void init0_kernel(int* bcnt, int nbk, float* out, int n) {
    int i = blockIdx.x * 256 + threadIdx.x;
    if (i < nbk) bcnt[i] = 0;
    if (i < n) out[i] = -__builtin_inff();
}

// ---- setup: bhist (first nebl blocks) + prep (rest) ---------------------
// prep: xb (bf16 h0), xq (fp8 h0 for gather), bp1/bp2 (frag-packed weights)
__global__ __launch_bounds__(256) void setup_kernel(
        const int* __restrict__ dst, int* __restrict__ bcnt, int E, int nbk, int nebl,
        const float* __restrict__ x, const float* __restrict__ votes,
        const float* __restrict__ W1l, const float* __restrict__ W1r,
        const float* __restrict__ W2l, const float* __restrict__ W2r,
        ushort_t* __restrict__ xb, uint_t* __restrict__ xq,
        ushort_t* __restrict__ bp1, ushort_t* __restrict__ bp2, int N) {
    __shared__ int lh[MAXBK];
    if ((int)blockIdx.x < nebl) {
        for (int i = threadIdx.x; i < nbk; i += 256) lh[i] = 0;
        __syncthreads();
        int base = blockIdx.x * EPB;
        int end = min(base + EPB, E);
        for (int k = base + threadIdx.x; k < end; k += 256)
            atomicAdd(&lh[dst[k] >> BSH], 1);
        __syncthreads();
        for (int i = threadIdx.x; i < nbk; i += 256)
            if (lh[i] > 0) atomicAdd(&bcnt[i], lh[i]);
        return;
    }
    int idx = ((int)blockIdx.x - nebl) * 256 + threadIdx.x;
    if (idx < N * IN_F) {
        int n = idx / IN_F, f = idx - n * IN_F;
        float v = (f < XD) ? x[n * XD + f] : votes[n];
        xb[idx] = f2bf(v);
    }
    if (idx < N * XQ_U) {
        int n = idx / XQ_U, c = idx - n * XQ_U;
        int f0 = 4 * c;
        float v0 = (f0 + 0 < XD) ? x[n * XD + f0 + 0] : votes[n];
        float v1 = (f0 + 1 < XD) ? x[n * XD + f0 + 1] : votes[n];
        float v2 = (f0 + 2 < XD) ? x[n * XD + f0 + 2] : votes[n];
        float v3 = (f0 + 3 < XD) ? x[n * XD + f0 + 3] : votes[n];
        int w = __builtin_amdgcn_cvt_pk_fp8_f32(v0, v1, 0, false);
        w = __builtin_amdgcn_cvt_pk_fp8_f32(v2, v3, w, true);
        xq[idx] = (uint_t)w;
    }
    if (idx < BP1_N) {
        int j = idx & 7;
        int lane = (idx >> 3) & 63;
        int rest = idx >> 9;
        int ks = rest % 7;
        int ct = rest / 7;
        int k = ks * 32 + (lane >> 4) * 8 + j;
        int col = ct * 16 + (lane & 15);
        float v = 0.f;
        if (k < IN_F) v = W1l[k * HID + col];
        else if (k < 2 * IN_F) v = W1r[(k - IN_F) * HID + col];
        bp1[idx] = f2bf(v);
    }
    int i2 = idx - BP1_N;
    if (i2 >= 0 && i2 < BP2_N) {
        int j = i2 & 7;
        int lane = (i2 >> 3) & 63;
        int ks = (i2 >> 9) & 3;
        int ct = i2 >> 11;
        int k = ks * 32 + (lane >> 4) * 8 + j;
        int col = ct * 16 + (lane & 15);
        float v = (col < OUTD) ? W2l[k * OUTD + col] : W2r[k * OUTD + (col - OUTD)];
        bp2[i2] = f2bf(v);
    }
}

// ---- A2: exclusive scan of bucket counts (one wave) ---------------------
__global__ __launch_bounds__(64) void bscan_kernel(const int* __restrict__ bcnt,
                                                   int* __restrict__ bbase,
                                                   int* __restrict__ brsv,
                                                   int* __restrict__ row_start,
                                                   int nbk, int N, int E) {
    int lane = threadIdx.x;
    int carry = 0;
    for (int b = 0; b < nbk; b += 64) {
        int i = b + lane;
        int orig = (i < nbk) ? bcnt[i] : 0;
        int v = orig;
#pragma unroll
        for (int d = 1; d < 64; d <<= 1) {
            int t = __shfl_up(v, d);
            if (lane >= d) v += t;
        }
        if (i < nbk) {
            int ex = carry + v - orig;
            bbase[i] = ex;
            brsv[i] = ex;
        }
        carry += __shfl(v, 63);
    }
    if (lane == 0) {
        bbase[nbk] = E;
        row_start[N] = E;
    }
}

// ---- A3: scatter edges into bucket-grouped ebuf (packed uint) -----------
__global__ __launch_bounds__(256) void bscatter_kernel(const int* __restrict__ src,
                                                       const int* __restrict__ dst,
                                                       int* __restrict__ brsv,
                                                       uint_t* __restrict__ ebuf,
                                                       int E, int nbk) {
    __shared__ int lh[MAXBK];
    __shared__ int lofs[MAXBK];
    for (int i = threadIdx.x; i < nbk; i += 256) lh[i] = 0;
    __syncthreads();
    int base = blockIdx.x * EPB;
    int end = min(base + EPB, E);
    for (int k = base + threadIdx.x; k < end; k += 256)
        atomicAdd(&lh[dst[k] >> BSH], 1);
    __syncthreads();
    for (int i = threadIdx.x; i < nbk; i += 256)
        if (lh[i] > 0) lofs[i] = atomicAdd(&brsv[i], lh[i]);
    __syncthreads();
    for (int k = base + threadIdx.x; k < end; k += 256) {
        int d = dst[k];
        int pos = atomicAdd(&lofs[d >> BSH], 1);
        ebuf[pos] = (uint_t)src[k] | ((uint_t)(d & (BNODES - 1)) << 26);
    }
}

// ---- B: per-bucket CSR build (row_start + sorted_src) -------------------
__global__ __launch_bounds__(256) void bbuild_kernel(const uint_t* __restrict__ ebuf,
                                                     const int* __restrict__ bbase,
                                                     int* __restrict__ row_start,
                                                     int* __restrict__ sorted_src,
                                                     int N) {
    __shared__ int nh[BNODES];
    __shared__ int cur[BNODES];
    int b = blockIdx.x;
    int e0 = bbase[b], e1 = bbase[b + 1];
    int nlo = b << BSH;
    int nloc = min(BNODES, N - nlo);
    if (threadIdx.x < BNODES) nh[threadIdx.x] = 0;
    __syncthreads();
    for (int k = e0 + threadIdx.x; k < e1; k += 256)
        atomicAdd(&nh[ebuf[k] >> 26], 1);
    __syncthreads();
    if (threadIdx.x < 64) {
        int lane = threadIdx.x;
        int orig = nh[lane];
        int v = orig;
#pragma unroll
        for (int d = 1; d < 64; d <<= 1) {
            int t = __shfl_up(v, d);
            if (lane >= d) v += t;
        }
        int ex = e0 + v - orig;
        cur[lane] = ex;
        if (lane < nloc) row_start[nlo + lane] = ex;
    }
    __syncthreads();
    for (int k = e0 + threadIdx.x; k < e1; k += 256) {
        uint_t e = ebuf[k];
        int pos = atomicAdd(&cur[e >> 26], 1);
        sorted_src[pos] = (int)(e & SRCMASK);
    }
}

// ---- fused: fp8 gather-mean (into LDS) + MFMA dense x2 ------------------
// h1 = relu([agg|h0] @ [W1l;W1r] + b1);  [u|vb] = h1 @ [W2l|W2r] (+b2 on vb)
#define T1_M 32
#define A_STRIDE_US 232
#define A_STRIDE_U  116
#define H1_STRIDE_US 136
__global__ __launch_bounds__(256) void fused1_kernel(
        const ushort_t* __restrict__ xb, const uint_t* __restrict__ xq,
        const int* __restrict__ row_start, const int* __restrict__ sorted_src,
        const ushort_t* __restrict__ bp1, const ushort_t* __restrict__ bp2,
        const float* __restrict__ b1, const float* __restrict__ b2,
        ushort_t* __restrict__ ub, float* __restrict__ vvb, int N) {
    __shared__ uint_t smem[T1_M * A_STRIDE_U];      // 14848 B
    __shared__ int rsh[T1_M + 1];
    int n0 = blockIdx.x * T1_M;
    const uint_t* xbu = (const uint_t*)xb;

    for (int i = threadIdx.x; i < T1_M * 54; i += 256) {
        int m = i / 54, c = i - m * 54;
        int n = n0 + m;
        smem[m * A_STRIDE_U + 54 + c] = (n < N) ? xbu[n * 54 + c] : 0u;
    }
    for (int i = threadIdx.x; i < T1_M * 4; i += 256) {
        int m = i >> 2, c = i & 3;
        smem[m * A_STRIDE_U + 108 + c] = 0u;
    }
    if (threadIdx.x <= T1_M) {
        int n = n0 + threadIdx.x;
        rsh[threadIdx.x] = row_start[min(n, N)];
    }
    __syncthreads();

    int lane = threadIdx.x & 63;
    int wid  = threadIdx.x >> 6;
    int h  = lane >> 5;
    int l2 = lane & 31;

    // phase B: fp8 gather-mean for this wave's 8 nodes -> LDS agg region
    int mq8 = wid * 8;
    for (int it = 0; it < 8; ++it) {
        int m = mq8 + it;
        int rs = rsh[m], re = rsh[m + 1];
        float a0 = 0.f, a1 = 0.f, a2 = 0.f, a3 = 0.f;
        for (int k0 = rs; k0 < re; k0 += 64) {
            int cnt = min(64, re - k0);
            int sl = sorted_src[k0 + min(lane, cnt - 1)];
            int t = 0;
            for (; t + 8 <= cnt; t += 8) {
                int s0 = __shfl(sl, t + h);
                int s1 = __shfl(sl, t + 2 + h);
                int s2 = __shfl(sl, t + 4 + h);
                int s3 = __shfl(sl, t + 6 + h);
                if (l2 < 27) {
                    uint_t w0 = xq[s0 * XQ_U + l2];
                    uint_t w1 = xq[s1 * XQ_U + l2];
                    uint_t w2 = xq[s2 * XQ_U + l2];
                    uint_t w3 = xq[s3 * XQ_U + l2];
                    f32x2 lo, hi;
                    lo = __builtin_amdgcn_cvt_pk_f32_fp8((int)w0, false);
                    hi = __builtin_amdgcn_cvt_pk_f32_fp8((int)w0, true);
                    a0 += lo[0]; a1 += lo[1]; a2 += hi[0]; a3 += hi[1];
                    lo = __builtin_amdgcn_cvt_pk_f32_fp8((int)w1, false);
                    hi = __builtin_amdgcn_cvt_pk_f32_fp8((int)w1, true);
                    a0 += lo[0]; a1 += lo[1]; a2 += hi[0]; a3 += hi[1];
                    lo = __builtin_amdgcn_cvt_pk_f32_fp8((int)w2, false);
                    hi = __builtin_amdgcn_cvt_pk_f32_fp8((int)w2, true);
                    a0 += lo[0]; a1 += lo[1]; a2 += hi[0]; a3 += hi[1];
                    lo = __builtin_amdgcn_cvt_pk_f32_fp8((int)w3, false);
                    hi = __builtin_amdgcn_cvt_pk_f32_fp8((int)w3, true);
                    a0 += lo[0]; a1 += lo[1]; a2 += hi[0]; a3 += hi[1];
                }
            }
            for (; t < cnt; t += 2) {
                int tt = min(t + h, cnt - 1);
                int s = __shfl(sl, tt);
                if (t + h < cnt && l2 < 27) {
                    uint_t w = xq[s * XQ_U + l2];
                    f32x2 lo = __builtin_amdgcn_cvt_pk_f32_fp8((int)w, false);
                    f32x2 hi = __builtin_amdgcn_cvt_pk_f32_fp8((int)w, true);
                    a0 += lo[0]; a1 += lo[1]; a2 += hi[0]; a3 += hi[1];
                }
            }
        }
        a0 += __shfl_xor(a0, 32);
        a1 += __shfl_xor(a1, 32);
        a2 += __shfl_xor(a2, 32);
        a3 += __shfl_xor(a3, 32);
        int node = n0 + m;
        if (node < N && l2 < 27) {
            float inv = 1.f / fmaxf((float)(re - rs), 1.f);
            ushort4 p;
            p.x = f2bf(a0 * inv);
            p.y = f2bf(a1 * inv);
            p.z = f2bf(a2 * inv);
            p.w = f2bf(a3 * inv);
            *(ushort4*)((ushort_t*)smem + m * A_STRIDE_US + 4 * l2) = p;
        }
    }
    __syncthreads();

    // phase C: MFMA layer 1
    int wrow = (wid & 1) << 4;
    int wcol = (wid >> 1) << 6;
    int arow = wrow + (lane & 15);
    int akoff = (lane >> 4) * 8;
    const ushort_t* sA = (const ushort_t*)smem;
    const bf16x8* bp1v = (const bf16x8*)bp1;

    f32x4 acc0 = {}, acc1 = {}, acc2_ = {}, acc3 = {};
    int ct0 = wcol >> 4;
#pragma unroll
    for (int ks = 0; ks < 7; ++ks) {
        bf16x8 af = *(const bf16x8*)(sA + arow * A_STRIDE_US + ks * 32 + akoff);
        bf16x8 bf0 = bp1v[((ct0 + 0) * 7 + ks) * 64 + lane];
        bf16x8 bf1 = bp1v[((ct0 + 1) * 7 + ks) * 64 + lane];
        bf16x8 bf2 = bp1v[((ct0 + 2) * 7 + ks) * 64 + lane];
        bf16x8 bf3 = bp1v[((ct0 + 3) * 7 + ks) * 64 + lane];
        acc0 = __builtin_amdgcn_mfma_f32_16x16x32_bf16(af, bf0, acc0, 0, 0, 0);
        acc1 = __builtin_amdgcn_mfma_f32_16x16x32_bf16(af, bf1, acc1, 0, 0, 0);
        acc2_ = __builtin_amdgcn_mfma_f32_16x16x32_bf16(af, bf2, acc2_, 0, 0, 0);
        acc3 = __builtin_amdgcn_mfma_f32_16x16x32_bf16(af, bf3, acc3, 0, 0, 0);
    }

    __syncthreads();
    ushort_t* sh1 = (ushort_t*)smem;
    {
        int colb = wcol + (lane & 15);
        int rowb = wrow + ((lane >> 4) << 2);
#pragma unroll
        for (int t = 0; t < 4; ++t) {
            f32x4 a = (t == 0) ? acc0 : (t == 1) ? acc1 : (t == 2) ? acc2_ : acc3;
            int col = colb + t * 16;
            float bj = b1[col];
#pragma unroll
            for (int r = 0; r < 4; ++r)
                sh1[(rowb + r) * H1_STRIDE_US + col] = f2bf(fmaxf(a[r] + bj, 0.f));
        }
    }
    __syncthreads();

    // phase D: MFMA layer 2 ([u|v+b2])
    const bf16x8* bp2v = (const bf16x8*)bp2;
    f32x4 dcc0 = {}, dcc1 = {}, dcc2 = {}, dcc3 = {};
#pragma unroll
    for (int ks = 0; ks < 4; ++ks) {
        bf16x8 af = *(const bf16x8*)(sh1 + arow * H1_STRIDE_US + ks * 32 + akoff);
        bf16x8 bf0 = bp2v[((ct0 + 0) * 4 + ks) * 64 + lane];
        bf16x8 bf1 = bp2v[((ct0 + 1) * 4 + ks) * 64 + lane];
        bf16x8 bf2 = bp2v[((ct0 + 2) * 4 + ks) * 64 + lane];
        bf16x8 bf3 = bp2v[((ct0 + 3) * 4 + ks) * 64 + lane];
        dcc0 = __builtin_amdgcn_mfma_f32_16x16x32_bf16(af, bf0, dcc0, 0, 0, 0);
        dcc1 = __builtin_amdgcn_mfma_f32_16x16x32_bf16(af, bf1, dcc1, 0, 0, 0);
        dcc2 = __builtin_amdgcn_mfma_f32_16x16x32_bf16(af, bf2, dcc2, 0, 0, 0);
        dcc3 = __builtin_amdgcn_mfma_f32_16x16x32_bf16(af, bf3, dcc3, 0, 0, 0);
    }

    {
        int colb = wcol + (lane & 15);
        int rowb = wrow + ((lane >> 4) << 2);
#pragma unroll
        for (int t = 0; t < 4; ++t) {
            f32x4 a = (t == 0) ? dcc0 : (t == 1) ? dcc1 : (t == 2) ? dcc2 : dcc3;
            int col = colb + t * 16;
#pragma unroll
            for (int r = 0; r < 4; ++r) {
                int n = n0 + rowb + r;
                if (n < N) {
                    if (col < OUTD) {
                        ub[(n << 6) + col] = f2bf(a[r]);
                    } else {
                        vvb[(n << 6) + (col - OUTD)] = a[r] + b2[col - OUTD];
                    }
                }
            }
        }
    }
}

// ---- gather-mean of u (bf16, 64 dims; wave per node) --------------------
__global__ __launch_bounds__(256) void gatheru_kernel(
        const ushort_t* __restrict__ ub,
        const int* __restrict__ row_start, const int* __restrict__ sorted_src,
        float* __restrict__ aggu, int N) {
    int node = (blockIdx.x * 256 + threadIdx.x) >> 6;
    int lane = threadIdx.x & 63;
    if (node >= N) return;
    int rs = row_start[node], re = row_start[node + 1];
    int g  = lane >> 4;
    int l4 = lane & 15;
    float a0 = 0.f, a1 = 0.f, a2 = 0.f, a3 = 0.f;
    for (int k0 = rs; k0 < re; k0 += 64) {
        int cnt = min(64, re - k0);
        int sl = sorted_src[k0 + min(lane, cnt - 1)];
        int t = 0;
        for (; t + 8 <= cnt; t += 8) {
            int s0 = __shfl(sl, t + g);
            int s1 = __shfl(sl, t + 4 + g);
            uint2 w0 = *(const uint2*)(ub + (s0 << 6) + 4 * l4);
            uint2 w1 = *(const uint2*)(ub + (s1 << 6) + 4 * l4);
            a0 += __uint_as_float(w0.x << 16) + __uint_as_float(w1.x << 16);
            a1 += __uint_as_float(w0.x & 0xffff0000u) + __uint_as_float(w1.x & 0xffff0000u);
            a2 += __uint_as_float(w0.y << 16) + __uint_as_float(w1.y << 16);
            a3 += __uint_as_float(w0.y & 0xffff0000u) + __uint_as_float(w1.y & 0xffff0000u);
        }
        for (; t < cnt; t += 4) {
            int tt = min(t + g, cnt - 1);
            int s = __shfl(sl, tt);
            if (t + g < cnt) {
                uint2 w = *(const uint2*)(ub + (s << 6) + 4 * l4);
                a0 += __uint_as_float(w.x << 16);
                a1 += __uint_as_float(w.x & 0xffff0000u);
                a2 += __uint_as_float(w.y << 16);
                a3 += __uint_as_float(w.y & 0xffff0000u);
            }
        }
    }
    a0 += __shfl_xor(a0, 16); a0 += __shfl_xor(a0, 32);
    a1 += __shfl_xor(a1, 16); a1 += __shfl_xor(a1, 32);
    a2 += __shfl_xor(a2, 16); a2 += __shfl_xor(a2, 32);
    a3 += __shfl_xor(a3, 16); a3 += __shfl_xor(a3, 32);
    float inv = 1.f / fmaxf((float)(re - rs), 1.f);
    if (lane < 16) {
        *(float4*)(aggu + (node << 6) + 4 * lane) =
            make_float4(a0 * inv, a1 * inv, a2 * inv, a3 * inv);
    }
}

// ---- finalize: h2 = aggu + vvb, then run-length segment-max -------------
__global__ __launch_bounds__(256) void finalize_kernel(
        const float* __restrict__ aggu, const float* __restrict__ vvb,
        const int* __restrict__ batch, float* __restrict__ out, int N) {
    int j  = threadIdx.x & 63;
    int nq = threadIdx.x >> 6;
    int n0 = blockIdx.x * SEG_NODES;
    int curg = -1;
    float curm = -__builtin_inff();
    for (int m = nq; m < SEG_NODES; m += 4) {
        int n = n0 + m;
        if (n >= N) break;
        int g = batch[n];
        float v = aggu[(n << 6) + j] + vvb[(n << 6) + j];
        if (g != curg) {
            if (curg >= 0) atomicMaxF(&out[(curg << 6) + j], curm);
            curg = g;
            curm = v;
        } else {
            curm = fmaxf(curm, v);
        }
    }
    if (curg >= 0) atomicMaxF(&out[(curg << 6) + j], curm);
}

static inline size_t align256(size_t v) { return (v + 255) & ~(size_t)255; }

extern "C" void kernel_launch(void* const* d_in, const int* in_sizes, int n_in,
                              void* d_out, int out_size, void* d_ws, size_t ws_size,
                              hipStream_t stream) {
    const float* x     = (const float*)d_in[0];
    const float* votes = (const float*)d_in[1];
    const int*   eidx  = (const int*)d_in[2];
    const int*   batch = (const int*)d_in[3];
    const float* W1l   = (const float*)d_in[4];
    const float* b1    = (const float*)d_in[5];
    const float* W1r   = (const float*)d_in[6];
    const float* W2l   = (const float*)d_in[7];
    const float* b2    = (const float*)d_in[8];
    const float* W2r   = (const float*)d_in[9];
    float* out = (float*)d_out;

    const int N = in_sizes[1];
    const int E = in_sizes[2] / 2;
    const int* src = eidx;
    const int* dst = eidx + E;
    const int nbk = (N + BNODES - 1) >> BSH;   // 782 for N=50000

    char* ws = (char*)d_ws;
    size_t off = 0;
    int* bcnt       = (int*)(ws + off); off = align256(off + (size_t)nbk * 4);
    int* bbase      = (int*)(ws + off); off = align256(off + (size_t)(nbk + 1) * 4);
    int* brsv       = (int*)(ws + off); off = align256(off + (size_t)nbk * 4);
    int* row_start  = (int*)(ws + off); off = align256(off + (size_t)(N + 1) * 4);
    uint_t* ebuf    = (uint_t*)(ws + off); off = align256(off + (size_t)E * 4);
    int* sorted_src = (int*)(ws + off); off = align256(off + (size_t)E * 4);
    ushort_t* xb    = (ushort_t*)(ws + off); off = align256(off + (size_t)N * IN_F * 2);
    uint_t* xq      = (uint_t*)(ws + off); off = align256(off + (size_t)N * XQ_U * 4);
    ushort_t* ub    = (ushort_t*)(ws + off); off = align256(off + (size_t)N * OUTD * 2);
    float* vvb      = (float*)(ws + off); off = align256(off + (size_t)N * OUTD * 4);
    float* aggu     = (float*)(ws + off); off = align256(off + (size_t)N * OUTD * 4);
    ushort_t* bp1   = (ushort_t*)(ws + off); off = align256(off + (size_t)BP1_N * 2);
    ushort_t* bp2   = (ushort_t*)(ws + off); off = align256(off + (size_t)BP2_N * 2);

    // init (bcnt zero + out=-inf)
    {
        int mx = max(nbk, out_size);
        init0_kernel<<<(mx + 255) / 256, 256, 0, stream>>>(bcnt, nbk, out, out_size);
    }

    // setup: bhist + xb/xq/bp1/bp2 conversions in one launch
    int nebl = (E + EPB - 1) / EPB;
    int prep_blocks = (N * IN_F + 255) / 256;
    setup_kernel<<<nebl + prep_blocks, 256, 0, stream>>>(dst, bcnt, E, nbk, nebl,
                                                         x, votes, W1l, W1r, W2l, W2r,
                                                         xb, xq, bp1, bp2, N);

    // CSR
    bscan_kernel<<<1, 64, 0, stream>>>(bcnt, bbase, brsv, row_start, nbk, N, E);
    bscatter_kernel<<<nebl, 256, 0, stream>>>(src, dst, brsv, ebuf, E, nbk);
    bbuild_kernel<<<nbk, 256, 0, stream>>>(ebuf, bbase, row_start, sorted_src, N);

    // fused fp8 gather + both dense matmuls via MFMA (agg + h1 stay in LDS)
    fused1_kernel<<<(N + T1_M - 1) / T1_M, 256, 0, stream>>>(xb, xq, row_start, sorted_src,
                                                             bp1, bp2, b1, b2, ub, vvb, N);
    // layer-2 aggregate (wave per node)
    gatheru_kernel<<<(N + 3) / 4, 256, 0, stream>>>(ub, row_start, sorted_src, aggu, N);

    // h2 = aggu + vvb, fused with segment-max
    finalize_kernel<<<(N + SEG_NODES - 1) / SEG_NODES, 256, 0, stream>>>(
        aggu, vvb, batch, out, N);
}